// Round 4
// baseline (249.094 us; speedup 1.0000x reference)
//
#include <hip/hip_runtime.h>

// Izhikevich spiking neuron scan — bitmask-staged stores, time-chunked.
// x: [T=512, N=65536] f32. out: [T, N] f32 spike train (0.0 / 1.0).
//
// R4 design: R3 sat at 2.5 TB/s regardless of vectorization/occupancy ->
// theory: vmcnt is FIFO, so the load->compute->store loop makes every
// load-wait also drain the previous stores (~500+cy HBM ack), serializing
// each wave at one batch per store-round-trip. Fix: no stores in the main
// loop. Spikes are 0/1 -> pack fire bits into 4 uint32 registers
// (4 neurons x 32 t), main loop = pure load+VALU (unroll 8 -> 8 KiB/wave
// in flight), then burst 32 float4 stores with no intervening waits
// (the harness fill kernel shows this pattern sustains 6.6 TB/s).
//
// Time-split: 16 chunks x TCH=32 + WARM=8 warmup steps. Map contracts
// state ~(5/512)/step -> seed error shrinks ~1e-16x over 8 steps, below
// fp32 ulp; output bit (v>=0.3, |v|<=~0.015) has ~20x margin anyway.

#define T_STEPS 512
#define N_NEUR  65536
#define NV      (N_NEUR / 4)     // float4 columns = 16384
#define DT      (1.0f / 512.0f)
#define TCH     32               // timesteps written per chunk
#define WARM    8                // warmup steps for chunk-seed convergence

__device__ __forceinline__ unsigned izi_step(float xt, float& v, float& r) {
    v = (4.0f * v * v + 5.0f * v + 1.4f - r + xt) * DT;
    // r = 0.02*(0.2v - v)*DT folds to a single mul: v * (0.02*(0.2-1)*DT)
    r = v * (0.02f * (0.2f - 1.0f) * DT);
    const bool fire = v >= 0.3f;
    if (fire) { v = -0.065f; r += 0.008f; }
    return fire ? 1u : 0u;
}

__global__ __launch_bounds__(256, 4) void izi_kernel(const float* __restrict__ x,
                                                     float* __restrict__ out) {
    const int g = blockIdx.x * 256 + threadIdx.x;   // float4-column, coalesced
    const int c = blockIdx.y;                       // time chunk 0..15
    const int tstart = c * TCH;

    const float4* xp = (const float4*)x + g;
    float4*       op = (float4*)out + g;

    float4 v = make_float4(-0.065f, -0.065f, -0.065f, -0.065f);
    float4 r = make_float4(0.0f, 0.0f, 0.0f, 0.0f);

    if (c > 0) {
        #pragma unroll
        for (int t = tstart - WARM; t < tstart; ++t) {
            const float4 xt = xp[(size_t)t * NV];
            izi_step(xt.x, v.x, r.x);
            izi_step(xt.y, v.y, r.y);
            izi_step(xt.z, v.z, r.z);
            izi_step(xt.w, v.w, r.w);
        }
    }

    // Main loop: loads + VALU only — no stores, so load waits never have to
    // drain store traffic through the FIFO vmcnt counter.
    unsigned m0 = 0, m1 = 0, m2 = 0, m3 = 0;   // fire bits: neuron j, bit = t_local
    #pragma unroll 8
    for (int tl = 0; tl < TCH; ++tl) {
        const float4 xt = xp[(size_t)(tstart + tl) * NV];
        m0 |= izi_step(xt.x, v.x, r.x) << tl;
        m1 |= izi_step(xt.y, v.y, r.y) << tl;
        m2 |= izi_step(xt.z, v.z, r.z) << tl;
        m3 |= izi_step(xt.w, v.w, r.w) << tl;
    }

    // Store burst: 32 float4 stores, fire-and-forget (no dependent waits
    // until end-of-kernel drain) — fill-kernel-like write streaming.
    #pragma unroll 8
    for (int tl = 0; tl < TCH; ++tl) {
        float4 o;
        o.x = (m0 >> tl) & 1u ? 1.0f : 0.0f;
        o.y = (m1 >> tl) & 1u ? 1.0f : 0.0f;
        o.z = (m2 >> tl) & 1u ? 1.0f : 0.0f;
        o.w = (m3 >> tl) & 1u ? 1.0f : 0.0f;
        op[(size_t)(tstart + tl) * NV] = o;
    }
}

extern "C" void kernel_launch(void* const* d_in, const int* in_sizes, int n_in,
                              void* d_out, int out_size, void* d_ws, size_t ws_size,
                              hipStream_t stream) {
    const float* x = (const float*)d_in[0];
    float* out = (float*)d_out;
    // grid: 16384 float4-cols / 256 threads = 64 blocks  x  16 time chunks
    // = 1024 blocks = 4 blocks/CU = 16 waves/CU.
    izi_kernel<<<dim3(NV / 256, T_STEPS / TCH), dim3(256), 0, stream>>>(x, out);
}

// Round 5
// 237.982 us; speedup vs baseline: 1.0467x; 1.0467x over previous
//
#include <hip/hip_runtime.h>
#include <stdint.h>

// Izhikevich spiking neuron scan — two-pass: bitpacked compute + linear expand.
//
// R5 rationale: R1-R4 all plateau at ~2.5 TB/s while the harness fill kernel
// (writes-only, linear) does 6.6 TB/s and the float4-copy ubench 6.3 TB/s.
// All our variants share strided (256 KiB/step) per-wave walks with mixed
// loads+stores in one kernel. Spikes are 1 bit -> split:
//   pass 1: recurrence, pure strided loads, spikes bitpacked to ws (4 MiB).
//   pass 2: per-row LINEAR expansion ws-bits -> f32 out (fill-like stream).
// This both isolates the slow path diagnostically and gives the write side
// (128 MiB, half of all traffic) the known-good 6.6 TB/s pattern.
//
// Time-split (16 chunks x 32 t + 8 warmup): map contracts state ~(5/512)/step,
// 8 steps shrink seed error ~1e-16x (below fp32 ulp); output bit (v>=0.3,
// |v|<=~0.015) has ~20x margin. Verified absmax=0.0 in R1-R4.

#define T_STEPS 512
#define N_NEUR  65536
#define NV      (N_NEUR / 4)      // float4 / uint4 columns = 16384
#define DT      (1.0f / 512.0f)
#define TCH     32                // timesteps per chunk
#define WARM    8                 // warmup steps per chunk
#define NCH     (T_STEPS / TCH)   // 16 chunks

__device__ __forceinline__ unsigned izi_step(float xt, float& v, float& r) {
    v = (4.0f * v * v + 5.0f * v + 1.4f - r + xt) * DT;
    r = v * (0.02f * (0.2f - 1.0f) * DT);   // folded r-update
    const bool fire = v >= 0.3f;
    if (fire) { v = -0.065f; r += 0.008f; }
    return fire ? 1u : 0u;
}

// ---- Pass 1: recurrence; pure loads in the hot loop; bitmask to ws. ----
__global__ __launch_bounds__(256, 4) void izi_compute(const float* __restrict__ x,
                                                      uint4* __restrict__ ws) {
    const int g = blockIdx.x * 256 + threadIdx.x;   // float4-column
    const int c = blockIdx.y;                       // time chunk
    const int tstart = c * TCH;
    const float4* xp = (const float4*)x + g;

    float4 v = make_float4(-0.065f, -0.065f, -0.065f, -0.065f);
    float4 r = make_float4(0.0f, 0.0f, 0.0f, 0.0f);

    if (c > 0) {
        #pragma unroll
        for (int t = tstart - WARM; t < tstart; ++t) {
            const float4 xt = xp[(size_t)t * NV];
            izi_step(xt.x, v.x, r.x);
            izi_step(xt.y, v.y, r.y);
            izi_step(xt.z, v.z, r.z);
            izi_step(xt.w, v.w, r.w);
        }
    }

    unsigned m0 = 0, m1 = 0, m2 = 0, m3 = 0;
    #pragma unroll 16    // 16 float4 loads in flight per wave (16 KiB)
    for (int tl = 0; tl < TCH; ++tl) {
        const float4 xt = xp[(size_t)(tstart + tl) * NV];
        m0 |= izi_step(xt.x, v.x, r.x) << tl;
        m1 |= izi_step(xt.y, v.y, r.y) << tl;
        m2 |= izi_step(xt.z, v.z, r.z) << tl;
        m3 |= izi_step(xt.w, v.w, r.w) << tl;
    }
    ws[(size_t)c * NV + g] = make_uint4(m0, m1, m2, m3);   // coalesced, 4 MiB total
}

// ---- Pass 2: expand bits -> f32. One block per row; purely linear writes. --
__global__ __launch_bounds__(256, 2) void izi_expand(const uint4* __restrict__ ws,
                                                     float4* __restrict__ out) {
    const int t  = blockIdx.x;        // 0..511
    const int c  = t >> 5;            // chunk
    const int tl = t & 31;            // bit index within word
    const uint4* wrow = ws + (size_t)c * NV;
    float4*      orow = out + (size_t)t * NV;

    #pragma unroll 8
    for (int i = threadIdx.x; i < NV; i += 256) {
        const uint4 w = wrow[i];      // L2/L3-resident (ws = 4 MiB)
        float4 o;
        o.x = ((w.x >> tl) & 1u) ? 1.0f : 0.0f;
        o.y = ((w.y >> tl) & 1u) ? 1.0f : 0.0f;
        o.z = ((w.z >> tl) & 1u) ? 1.0f : 0.0f;
        o.w = ((w.w >> tl) & 1u) ? 1.0f : 0.0f;
        orow[i] = o;                  // linear 256-KiB stream per block
    }
}

// ---- Fallback (R3 fused) if ws is too small for the 4 MiB bitmask. ----
__global__ __launch_bounds__(256, 4) void izi_fused(const float* __restrict__ x,
                                                    float* __restrict__ out) {
    const int g = blockIdx.x * 256 + threadIdx.x;
    const int c = blockIdx.y;
    const int tstart = c * TCH;
    const float4* xp = (const float4*)x + g;
    float4*       op = (float4*)out + g;

    float4 v = make_float4(-0.065f, -0.065f, -0.065f, -0.065f);
    float4 r = make_float4(0.0f, 0.0f, 0.0f, 0.0f);

    if (c > 0) {
        #pragma unroll
        for (int t = tstart - WARM; t < tstart; ++t) {
            const float4 xt = xp[(size_t)t * NV];
            izi_step(xt.x, v.x, r.x);
            izi_step(xt.y, v.y, r.y);
            izi_step(xt.z, v.z, r.z);
            izi_step(xt.w, v.w, r.w);
        }
    }
    #pragma unroll 4
    for (int t = tstart; t < tstart + TCH; ++t) {
        const float4 xt = xp[(size_t)t * NV];
        float4 o;
        o.x = izi_step(xt.x, v.x, r.x) ? 1.0f : 0.0f;
        o.y = izi_step(xt.y, v.y, r.y) ? 1.0f : 0.0f;
        o.z = izi_step(xt.z, v.z, r.z) ? 1.0f : 0.0f;
        o.w = izi_step(xt.w, v.w, r.w) ? 1.0f : 0.0f;
        op[(size_t)t * NV] = o;
    }
}

extern "C" void kernel_launch(void* const* d_in, const int* in_sizes, int n_in,
                              void* d_out, int out_size, void* d_ws, size_t ws_size,
                              hipStream_t stream) {
    const float* x = (const float*)d_in[0];
    float* out = (float*)d_out;
    const size_t need = (size_t)NCH * NV * sizeof(uint4);   // 4 MiB
    if (ws_size >= need) {
        izi_compute<<<dim3(NV / 256, NCH), dim3(256), 0, stream>>>(x, (uint4*)d_ws);
        izi_expand<<<dim3(T_STEPS), dim3(256), 0, stream>>>((const uint4*)d_ws,
                                                            (float4*)out);
    } else {
        izi_fused<<<dim3(NV / 256, NCH), dim3(256), 0, stream>>>(x, out);
    }
}

// Round 6
// 235.009 us; speedup vs baseline: 1.0599x; 1.0127x over previous
//
#include <hip/hip_runtime.h>

// Izhikevich spiking neuron scan — explicit 8-deep register prefetch ring.
// x: [T=512, N=65536] f32. out: [T, N] f32 spike train (0.0 / 1.0).
//
// R6 theory: R4/R5 compute kernels report VGPR=36 — too few to hold even 4
// in-flight float4 loads, i.e. the allocator re-rolled the unrolled loads
// into a ~2-outstanding reuse chain (~2 KiB/wave in flight). Little's law
// at ~2-4k cy loaded latency then caps reads at the observed ~2.5 TB/s.
// Fix: an explicit prefetch ring buf[8] (load t+8 before consuming t) whose
// liveness forces 8 loads (8 KiB/wave) outstanding in steady state
// -> ~128 KiB/CU at 16 waves/CU, far past the ~10 B/cy/CU needed for peak.
//
// Time-split (16 chunks x TCH=32 + WARM=8): the map contracts prior state by
// ~(5/512)/step, so 8 warmup steps shrink seed error ~1e-16x (below fp32
// ulp); the output bit (v>=0.3, |v|<=~0.015) has ~20x margin regardless.
// absmax=0.0 verified in R1-R5.

#define T_STEPS 512
#define N_NEUR  65536
#define NV      (N_NEUR / 4)      // float4 columns = 16384
#define DT      (1.0f / 512.0f)
#define TCH     32                // timesteps per chunk
#define WARM    8                 // warmup steps per chunk
#define NCH     (T_STEPS / TCH)   // 16
#define PF      8                 // prefetch ring depth (float4 loads in flight)

__device__ __forceinline__ float izi_step(float xt, float& v, float& r) {
    v = (4.0f * v * v + 5.0f * v + 1.4f - r + xt) * DT;
    r = v * (0.02f * (0.2f - 1.0f) * DT);   // folded r-update
    const bool fire = v >= 0.3f;
    if (fire) { v = -0.065f; r += 0.008f; }
    return fire ? 1.0f : 0.0f;
}

__global__ __launch_bounds__(256, 4) void izi_kernel(const float* __restrict__ x,
                                                     float* __restrict__ out) {
    const int g = blockIdx.x * 256 + threadIdx.x;   // float4-column, coalesced
    const int c = blockIdx.y;                       // time chunk 0..15
    const int tstart = c * TCH;

    const float4* xp = (const float4*)x + g;
    float4*       op = (float4*)out + g;

    float4 v = make_float4(-0.065f, -0.065f, -0.065f, -0.065f);
    float4 r = make_float4(0.0f, 0.0f, 0.0f, 0.0f);

    if (c > 0) {
        // Warmup: batch all 8 loads first (independent), then the serial chain.
        float4 wb[WARM];
        #pragma unroll
        for (int j = 0; j < WARM; ++j)
            wb[j] = xp[(size_t)(tstart - WARM + j) * NV];
        #pragma unroll
        for (int j = 0; j < WARM; ++j) {
            izi_step(wb[j].x, v.x, r.x);
            izi_step(wb[j].y, v.y, r.y);
            izi_step(wb[j].z, v.z, r.z);
            izi_step(wb[j].w, v.w, r.w);
        }
    }

    // Prefetch ring: fill 8 slots, then each iteration consumes slot tl&7 and
    // immediately re-issues it for t+8. Slot liveness spans 8 iterations, so
    // the allocator MUST keep 8 loads (8 KiB/wave) in flight — it cannot
    // re-roll them into a short reuse chain like R3-R5's unrolled loops.
    float4 buf[PF];
    #pragma unroll
    for (int j = 0; j < PF; ++j)
        buf[j] = xp[(size_t)(tstart + j) * NV];

    #pragma unroll
    for (int tl = 0; tl < TCH; ++tl) {
        const float4 cur = buf[tl & (PF - 1)];
        if (tl + PF < TCH)                       // compile-time per unrolled iter
            buf[tl & (PF - 1)] = xp[(size_t)(tstart + tl + PF) * NV];
        float4 o;
        o.x = izi_step(cur.x, v.x, r.x);
        o.y = izi_step(cur.y, v.y, r.y);
        o.z = izi_step(cur.z, v.z, r.z);
        o.w = izi_step(cur.w, v.w, r.w);
        op[(size_t)(tstart + tl) * NV] = o;      // interleaved stores (R3 > R4)
    }
}

extern "C" void kernel_launch(void* const* d_in, const int* in_sizes, int n_in,
                              void* d_out, int out_size, void* d_ws, size_t ws_size,
                              hipStream_t stream) {
    const float* x = (const float*)d_in[0];
    float* out = (float*)d_out;
    // 64 neuron-blocks x 16 time chunks = 1024 blocks = 4 blocks/CU
    // = 16 waves/CU at launch_bounds(256,4) (VGPR cap 128).
    izi_kernel<<<dim3(NV / 256, NCH), dim3(256), 0, stream>>>(x, out);
}